// Round 2
// baseline (107.139 us; speedup 1.0000x reference)
//
#include <hip/hip_runtime.h>
#include <math.h>

#define N_NODES 8192
#define KNN 9
#define TILE 64

// Fully-unrolled, statically-indexed carry-bubble insert into sorted-ascending
// top-9 (strict <, so equal keys keep the incumbent = lower index first, which
// matches jax.lax.top_k tie-breaking when candidates arrive in ascending index
// order).
__device__ __forceinline__ void insert9(float (&td)[9], int (&ti)[9], float d, int idx) {
  float cd = d; int ci = idx;
#pragma unroll
  for (int k = 0; k < 9; ++k) {
    bool c = cd < td[k];
    float od = td[k]; int oi = ti[k];
    td[k] = c ? cd : od;  ti[k] = c ? ci : oi;
    cd = c ? od : cd;     ci = c ? oi : ci;
  }
}

// K1: x[B,C,H,W] -> xf[N,C] via LDS tile transpose (coalesced both ways);
// sq[n] = ||xf[n]||^2 ; zero deg.
__global__ __launch_bounds__(256) void k_prep(const float* __restrict__ x,
                                              float* __restrict__ xf,
                                              float* __restrict__ sq,
                                              int* __restrict__ deg) {
  __shared__ float t[64][65];
  const int b = blockIdx.x >> 4;
  const int hw0 = (blockIdx.x & 15) * 64;
  const int c0 = threadIdx.x >> 6;      // 0..3
  const int hwl = threadIdx.x & 63;
  // read: lanes along hw -> 256B contiguous per wave
#pragma unroll
  for (int i = 0; i < 16; ++i) {
    int c = i * 4 + c0;
    t[c][hwl] = x[((size_t)(b * 64 + c)) * 1024 + hw0 + hwl];
  }
  __syncthreads();
  const int wave = threadIdx.x >> 6;    // 0..3
  const int lane = threadIdx.x & 63;    // channel
#pragma unroll
  for (int i = 0; i < 16; ++i) {
    int r = i * 4 + wave;               // hw row within tile
    float v = t[lane][r];
    int n = b * 1024 + hw0 + r;
    xf[(size_t)n * 64 + lane] = v;      // lanes along c -> 256B contiguous
    float s = v * v;
#pragma unroll
    for (int m = 1; m < 64; m <<= 1) s += __shfl_xor(s, m);
    if (lane == 0) sq[n] = s;
  }
  int tid = blockIdx.x * 256 + threadIdx.x;
  if (tid < N_NODES) deg[tid] = 0;
}

// K2: per-batch chunked KNN. grid = (32 query-chunks of 256, P candidate-chunks).
// Each thread owns one query (vector in 64 VGPRs), scans its batch's candidate
// chunk from a broadcast LDS tile, keeps a private sorted top-9.
__global__ __launch_bounds__(256) void k_knn(const float* __restrict__ xf,
                                             const float* __restrict__ sq,
                                             float* __restrict__ pd,
                                             int* __restrict__ pi, int P) {
  __shared__ float lx[TILE * 64];
  __shared__ float lsq[TILE];
  const int qbase = blockIdx.x * 256;
  const int p = blockIdx.y;
  const int q = qbase + (int)threadIdx.x;
  // batch of this block's queries (256-chunks never straddle batch boundaries;
  // sole exception is node 8191 = batch 8, masked below)
  const int b = (8 * qbase) / 8191;
  const int bstart = (b * 8191 + 7) / 8;            // ceil(b*8191/8)
  int bend = ((b + 1) * 8191 + 7) / 8;              // start of next batch
  if (bend > N_NODES - 1) bend = N_NODES - 1;       // exclude node 8191 (batch 8)

  const int len = bend - bstart;
  const int csz = (len + P - 1) / P;
  const int cs = bstart + p * csz;
  const int ce = min(cs + csz, bend);

  float qv[64];
  const float4* qp = reinterpret_cast<const float4*>(xf + (size_t)q * 64);
#pragma unroll
  for (int i = 0; i < 16; ++i) {
    float4 v = qp[i];
    qv[4 * i + 0] = v.x; qv[4 * i + 1] = v.y; qv[4 * i + 2] = v.z; qv[4 * i + 3] = v.w;
  }
  const float sqq = sq[q];

  float td[9]; int ti[9];
#pragma unroll
  for (int k = 0; k < 9; ++k) { td[k] = 3.0e38f; ti[k] = 0x7fffffff; }

  for (int ts = cs; ts < ce; ts += TILE) {
    const int tc = min(TILE, ce - ts);
    __syncthreads();
    const float4* src4 = reinterpret_cast<const float4*>(xf + (size_t)ts * 64);
    float4* dst4 = reinterpret_cast<float4*>(lx);
    for (int t = threadIdx.x; t < tc * 16; t += 256) dst4[t] = src4[t];
    for (int t = threadIdx.x; t < tc; t += 256) lsq[t] = sq[ts + t];
    __syncthreads();
#pragma unroll 2
    for (int j = 0; j < tc; ++j) {
      const float4* cj = reinterpret_cast<const float4*>(lx + j * 64);
      float a0 = 0.f, a1 = 0.f, a2 = 0.f, a3 = 0.f;
#pragma unroll
      for (int i = 0; i < 16; ++i) {
        float4 v = cj[i];
        a0 = fmaf(qv[4 * i + 0], v.x, a0);
        a1 = fmaf(qv[4 * i + 1], v.y, a1);
        a2 = fmaf(qv[4 * i + 2], v.z, a2);
        a3 = fmaf(qv[4 * i + 3], v.w, a3);
      }
      float dot = (a0 + a1) + (a2 + a3);
      float d2 = fmaf(-2.f, dot, sqq + lsq[j]);
      if (d2 < td[8]) insert9(td, ti, d2, ts + j);
    }
  }
  if (q != N_NODES - 1) {
    int base = (p * N_NODES + q) * KNN;
#pragma unroll
    for (int k = 0; k < 9; ++k) { pd[base + k] = td[k]; pi[base + k] = ti[k]; }
  }
}

// K3: merge P sorted partial lists -> final 9; count degrees (src != dst).
__global__ __launch_bounds__(256) void k_merge(const float* __restrict__ pd,
                                               const int* __restrict__ pi,
                                               int* __restrict__ idxf,
                                               int* __restrict__ deg, int P) {
  int q = blockIdx.x * 256 + threadIdx.x;
  float td[9]; int ti[9];
#pragma unroll
  for (int k = 0; k < 9; ++k) { td[k] = 3.0e38f; ti[k] = 0x7fffffff; }
  if (q == N_NODES - 1) {
    // batch 8 = {8191}: self first, then -inf ties filled with indices 0..7
    ti[0] = N_NODES - 1;
#pragma unroll
    for (int k = 1; k < 9; ++k) ti[k] = k - 1;
  } else {
    for (int p = 0; p < P; ++p) {
      int base = (p * N_NODES + q) * KNN;
#pragma unroll
      for (int k = 0; k < 9; ++k) {
        float cd = pd[base + k];
        if (!(cd < td[8])) break;   // list sorted: rest can't insert either
        insert9(td, ti, cd, pi[base + k]);
      }
    }
  }
#pragma unroll
  for (int k = 0; k < 9; ++k) idxf[q * KNN + k] = ti[k];
#pragma unroll
  for (int k = 0; k < 9; ++k) {
    int s = ti[k];
    if (s != q) atomicAdd(&deg[s], 1);
  }
}

// K4 (fused gather + output GEMM):
// phase 1: g[t] = sum_k (-dis[s_k] * dis[t]) * xf[s_k]  -> straight into LDS
// phase 2: out = xf @ W0 + g @ W1 + bias
__global__ __launch_bounds__(256) void k_gout(const float* __restrict__ xf,
                                              const int* __restrict__ idxf,
                                              const int* __restrict__ deg,
                                              const float* __restrict__ W0,
                                              const float* __restrict__ W1,
                                              const float* __restrict__ bias,
                                              float* __restrict__ out) {
  __shared__ float w0[64 * 64];
  __shared__ float w1[64 * 64];
  __shared__ float sx[16 * 65];   // +1 pad: kills 4-way bank conflict on row reads
  __shared__ float sg[16 * 65];
  const int nb = blockIdx.x * 16;

  // stage weights
  float4* w04 = reinterpret_cast<float4*>(w0);
  float4* w14 = reinterpret_cast<float4*>(w1);
  const float4* W04 = reinterpret_cast<const float4*>(W0);
  const float4* W14 = reinterpret_cast<const float4*>(W1);
  for (int t = threadIdx.x; t < 1024; t += 256) { w04[t] = W04[t]; w14[t] = W14[t]; }
  // stage x tile
  for (int t = threadIdx.x; t < 1024; t += 256) {
    int ln = t >> 6, c = t & 63;
    sx[ln * 65 + c] = xf[(size_t)(nb + ln) * 64 + c];
  }
  // phase 1: gather into sg. thread = (node ln, channel-quad c4)
  {
    int ln = threadIdx.x >> 4, c4 = threadIdx.x & 15;
    int n = nb + ln;
    int dt = deg[n];
    float dis_t = dt > 0 ? 1.f / sqrtf((float)dt) : 0.f;
    float ax = 0.f, ay = 0.f, az = 0.f, aw = 0.f;
#pragma unroll
    for (int k = 0; k < 9; ++k) {
      int s = idxf[n * KNN + k];
      if (s == n) continue;                    // self loop: w=0 -> norm 0
      int ds = deg[s];
      float dis_s = ds > 0 ? 1.f / sqrtf((float)ds) : 0.f;
      float w = -dis_s * dis_t;
      float4 v = reinterpret_cast<const float4*>(xf + (size_t)s * 64)[c4];
      ax = fmaf(w, v.x, ax); ay = fmaf(w, v.y, ay);
      az = fmaf(w, v.z, az); aw = fmaf(w, v.w, aw);
    }
    sg[ln * 65 + c4 * 4 + 0] = ax;
    sg[ln * 65 + c4 * 4 + 1] = ay;
    sg[ln * 65 + c4 * 4 + 2] = az;
    sg[ln * 65 + c4 * 4 + 3] = aw;
  }
  __syncthreads();
  // phase 2: GEMM
  int ln = threadIdx.x >> 4, o4 = threadIdx.x & 15;
  float4 acc = reinterpret_cast<const float4*>(bias)[o4];
#pragma unroll
  for (int c = 0; c < 64; ++c) {
    float xv = sx[ln * 65 + c];
    float gv = sg[ln * 65 + c];
    float4 v0 = reinterpret_cast<const float4*>(w0 + c * 64)[o4];
    float4 v1 = reinterpret_cast<const float4*>(w1 + c * 64)[o4];
    acc.x = fmaf(xv, v0.x, acc.x); acc.y = fmaf(xv, v0.y, acc.y);
    acc.z = fmaf(xv, v0.z, acc.z); acc.w = fmaf(xv, v0.w, acc.w);
    acc.x = fmaf(gv, v1.x, acc.x); acc.y = fmaf(gv, v1.y, acc.y);
    acc.z = fmaf(gv, v1.z, acc.z); acc.w = fmaf(gv, v1.w, acc.w);
  }
  reinterpret_cast<float4*>(out)[(size_t)(nb + ln) * 16 + o4] = acc;
}

extern "C" void kernel_launch(void* const* d_in, const int* in_sizes, int n_in,
                              void* d_out, int out_size, void* d_ws, size_t ws_size,
                              hipStream_t stream) {
  const float* x    = (const float*)d_in[0];
  const float* W0   = (const float*)d_in[1];
  const float* W1   = (const float*)d_in[2];
  const float* bias = (const float*)d_in[3];
  float* out = (float*)d_out;
  char* ws = (char*)d_ws;

  // workspace layout
  float* xf   = (float*)(ws);                       // 8192*64*4 = 2,097,152
  float* sq   = (float*)(ws + 2097152);             // 32,768
  int*   deg  = (int*)  (ws + 2129920);             // 32,768
  int*   idxf = (int*)  (ws + 2162688);             // 8192*9*4 = 294,912
  char*  pbase = ws + 2457600;                      // partial top-9 lists

  int P = 32;   // candidate chunks: occupancy lever (32 -> 4 blocks/CU in k_knn)
  while (P > 1) {
    size_t need = 2457600 + (size_t)P * N_NODES * KNN * 8;
    if (need <= ws_size) break;
    P >>= 1;
  }
  float* pd = (float*)pbase;
  int*   pi = (int*)(pbase + (size_t)P * N_NODES * KNN * 4);

  k_prep  <<<128, 256, 0, stream>>>(x, xf, sq, deg);
  k_knn   <<<dim3(32, P), 256, 0, stream>>>(xf, sq, pd, pi, P);
  k_merge <<<32, 256, 0, stream>>>(pd, pi, idxf, deg, P);
  k_gout  <<<512, 256, 0, stream>>>(xf, idxf, deg, W0, W1, bias, out);
}

// Round 3
// 85.258 us; speedup vs baseline: 1.2566x; 1.2566x over previous
//
#include <hip/hip_runtime.h>
#include <math.h>

#define N_NODES 8192
#define KNN 9
#define TILE 64

// Fully-unrolled, statically-indexed carry-bubble insert into sorted-ascending
// top-9 (strict <, so equal keys keep the incumbent = lower index first, which
// matches jax.lax.top_k tie-breaking when candidates arrive in ascending index
// order).
__device__ __forceinline__ void insert9(float (&td)[9], int (&ti)[9], float d, int idx) {
  float cd = d; int ci = idx;
#pragma unroll
  for (int k = 0; k < 9; ++k) {
    bool c = cd < td[k];
    float od = td[k]; int oi = ti[k];
    td[k] = c ? cd : od;  ti[k] = c ? ci : oi;
    cd = c ? od : cd;     ci = c ? oi : ci;
  }
}

// K1: x[B,C,H,W] -> xf[N,C] via LDS tile transpose (coalesced both ways);
// sq[n] = ||xf[n]||^2 ; zero deg.
__global__ __launch_bounds__(256) void k_prep(const float* __restrict__ x,
                                              float* __restrict__ xf,
                                              float* __restrict__ sq,
                                              int* __restrict__ deg) {
  __shared__ float t[64][65];
  const int b = blockIdx.x >> 4;
  const int hw0 = (blockIdx.x & 15) * 64;
  const int c0 = threadIdx.x >> 6;      // 0..3
  const int hwl = threadIdx.x & 63;
#pragma unroll
  for (int i = 0; i < 16; ++i) {
    int c = i * 4 + c0;
    t[c][hwl] = x[((size_t)(b * 64 + c)) * 1024 + hw0 + hwl];
  }
  __syncthreads();
  const int wave = threadIdx.x >> 6;    // 0..3
  const int lane = threadIdx.x & 63;    // channel
#pragma unroll
  for (int i = 0; i < 16; ++i) {
    int r = i * 4 + wave;               // hw row within tile
    float v = t[lane][r];
    int n = b * 1024 + hw0 + r;
    xf[(size_t)n * 64 + lane] = v;      // lanes along c -> 256B contiguous
    float s = v * v;
#pragma unroll
    for (int m = 1; m < 64; m <<= 1) s += __shfl_xor(s, m);
    if (lane == 0) sq[n] = s;
  }
  int tid = blockIdx.x * 256 + threadIdx.x;
  if (tid < N_NODES) deg[tid] = 0;
}

// K2: per-batch chunked KNN. grid = (32 query-chunks of 256, P candidate-chunks).
// Each thread owns one query (vector in 64 VGPRs), scans its batch's candidate
// chunk from a broadcast LDS tile, keeps a private sorted top-9.
// Partials are written QUERY-MAJOR: pd[(q*P+p)*9 + k], so the merge wave reads
// all of query q's lists from one contiguous 1152B window.
__global__ __launch_bounds__(256) void k_knn(const float* __restrict__ xf,
                                             const float* __restrict__ sq,
                                             float* __restrict__ pd,
                                             int* __restrict__ pi, int P) {
  __shared__ float lx[TILE * 64];
  __shared__ float lsq[TILE];
  const int qbase = blockIdx.x * 256;
  const int p = blockIdx.y;
  const int q = qbase + (int)threadIdx.x;
  const int b = (8 * qbase) / 8191;
  const int bstart = (b * 8191 + 7) / 8;            // ceil(b*8191/8)
  int bend = ((b + 1) * 8191 + 7) / 8;              // start of next batch
  if (bend > N_NODES - 1) bend = N_NODES - 1;       // exclude node 8191 (batch 8)

  const int len = bend - bstart;
  const int csz = (len + P - 1) / P;
  const int cs = bstart + p * csz;
  const int ce = min(cs + csz, bend);

  float qv[64];
  const float4* qp = reinterpret_cast<const float4*>(xf + (size_t)q * 64);
#pragma unroll
  for (int i = 0; i < 16; ++i) {
    float4 v = qp[i];
    qv[4 * i + 0] = v.x; qv[4 * i + 1] = v.y; qv[4 * i + 2] = v.z; qv[4 * i + 3] = v.w;
  }
  const float sqq = sq[q];

  float td[9]; int ti[9];
#pragma unroll
  for (int k = 0; k < 9; ++k) { td[k] = 3.0e38f; ti[k] = 0x7fffffff; }

  for (int ts = cs; ts < ce; ts += TILE) {
    const int tc = min(TILE, ce - ts);
    __syncthreads();
    const float4* src4 = reinterpret_cast<const float4*>(xf + (size_t)ts * 64);
    float4* dst4 = reinterpret_cast<float4*>(lx);
    for (int t = threadIdx.x; t < tc * 16; t += 256) dst4[t] = src4[t];
    for (int t = threadIdx.x; t < tc; t += 256) lsq[t] = sq[ts + t];
    __syncthreads();
#pragma unroll 2
    for (int j = 0; j < tc; ++j) {
      const float4* cj = reinterpret_cast<const float4*>(lx + j * 64);
      float a0 = 0.f, a1 = 0.f, a2 = 0.f, a3 = 0.f;
#pragma unroll
      for (int i = 0; i < 16; ++i) {
        float4 v = cj[i];
        a0 = fmaf(qv[4 * i + 0], v.x, a0);
        a1 = fmaf(qv[4 * i + 1], v.y, a1);
        a2 = fmaf(qv[4 * i + 2], v.z, a2);
        a3 = fmaf(qv[4 * i + 3], v.w, a3);
      }
      float dot = (a0 + a1) + (a2 + a3);
      float d2 = fmaf(-2.f, dot, sqq + lsq[j]);
      if (d2 < td[8]) insert9(td, ti, d2, ts + j);
    }
  }
  if (q != N_NODES - 1) {
    size_t base = ((size_t)q * P + p) * KNN;
#pragma unroll
    for (int k = 0; k < 9; ++k) { pd[base + k] = td[k]; pi[base + k] = ti[k]; }
  }
}

// K3: wave-cooperative P-way merge. One wave per query (4 queries/block).
// Lane p holds partial list p (sorted); 9 rounds of 5-step shfl argmin over
// (d, lane) — lower lane wins ties = lower chunk = lower candidate index,
// matching top_k order. Winning lane pops its head via static unrolled shift.
// Requires P <= 32 (reduction spans lanes 0..31; upper lanes hold +inf and
// any garbage winner there never passes the lane==r / write guards).
__global__ __launch_bounds__(256) void k_merge(const float* __restrict__ pd,
                                               const int* __restrict__ pi,
                                               int* __restrict__ idxf,
                                               int* __restrict__ deg, int P) {
  const int lane = threadIdx.x & 63;
  const int q = blockIdx.x * 4 + (threadIdx.x >> 6);

  if (q == N_NODES - 1) {
    // batch 8 = {8191}: self first, then -inf ties filled with indices 0..7
    if (lane < KNN) {
      int s = (lane == 0) ? (N_NODES - 1) : (lane - 1);
      idxf[q * KNN + lane] = s;
      if (s != q) atomicAdd(&deg[s], 1);
    }
    return;
  }

  float ld[9]; int li[9];
  {
    int pl = lane < P ? lane : (P - 1);
    size_t base = ((size_t)q * P + pl) * KNN;
#pragma unroll
    for (int k = 0; k < 9; ++k) { ld[k] = pd[base + k]; li[k] = pi[base + k]; }
    if (lane >= P) {
#pragma unroll
      for (int k = 0; k < 9; ++k) ld[k] = 3.2e38f;
    }
  }

#pragma unroll
  for (int r = 0; r < 9; ++r) {
    float d = ld[0]; int bi = li[0]; int bl = lane;
#pragma unroll
    for (int m = 1; m < 32; m <<= 1) {
      float od = __shfl_xor(d, m);
      int obi = __shfl_xor(bi, m);
      int obl = __shfl_xor(bl, m);
      bool take = (od < d) || (od == d && obl < bl);
      d = take ? od : d; bi = take ? obi : bi; bl = take ? obl : bl;
    }
    if (lane == r) {
      idxf[q * KNN + r] = bi;
      if (bi != q) atomicAdd(&deg[bi], 1);
    }
    if (lane == bl) {
#pragma unroll
      for (int k = 0; k < 8; ++k) { ld[k] = ld[k + 1]; li[k] = li[k + 1]; }
      ld[8] = 3.2e38f;
    }
  }
}

// K4 (fused gather + output GEMM):
// phase 1: g[t] = sum_k (-dis[s_k] * dis[t]) * xf[s_k]  -> straight into LDS
// phase 2: out = xf @ W0 + g @ W1 + bias
__global__ __launch_bounds__(256) void k_gout(const float* __restrict__ xf,
                                              const int* __restrict__ idxf,
                                              const int* __restrict__ deg,
                                              const float* __restrict__ W0,
                                              const float* __restrict__ W1,
                                              const float* __restrict__ bias,
                                              float* __restrict__ out) {
  __shared__ float w0[64 * 64];
  __shared__ float w1[64 * 64];
  __shared__ float sx[16 * 65];   // +1 pad: kills 4-way bank conflict on row reads
  __shared__ float sg[16 * 65];
  const int nb = blockIdx.x * 16;

  float4* w04 = reinterpret_cast<float4*>(w0);
  float4* w14 = reinterpret_cast<float4*>(w1);
  const float4* W04 = reinterpret_cast<const float4*>(W0);
  const float4* W14 = reinterpret_cast<const float4*>(W1);
  for (int t = threadIdx.x; t < 1024; t += 256) { w04[t] = W04[t]; w14[t] = W14[t]; }
  for (int t = threadIdx.x; t < 1024; t += 256) {
    int ln = t >> 6, c = t & 63;
    sx[ln * 65 + c] = xf[(size_t)(nb + ln) * 64 + c];
  }
  {
    int ln = threadIdx.x >> 4, c4 = threadIdx.x & 15;
    int n = nb + ln;
    int dt = deg[n];
    float dis_t = dt > 0 ? 1.f / sqrtf((float)dt) : 0.f;
    float ax = 0.f, ay = 0.f, az = 0.f, aw = 0.f;
#pragma unroll
    for (int k = 0; k < 9; ++k) {
      int s = idxf[n * KNN + k];
      if (s == n) continue;                    // self loop: w=0 -> norm 0
      int ds = deg[s];
      float dis_s = ds > 0 ? 1.f / sqrtf((float)ds) : 0.f;
      float w = -dis_s * dis_t;
      float4 v = reinterpret_cast<const float4*>(xf + (size_t)s * 64)[c4];
      ax = fmaf(w, v.x, ax); ay = fmaf(w, v.y, ay);
      az = fmaf(w, v.z, az); aw = fmaf(w, v.w, aw);
    }
    sg[ln * 65 + c4 * 4 + 0] = ax;
    sg[ln * 65 + c4 * 4 + 1] = ay;
    sg[ln * 65 + c4 * 4 + 2] = az;
    sg[ln * 65 + c4 * 4 + 3] = aw;
  }
  __syncthreads();
  int ln = threadIdx.x >> 4, o4 = threadIdx.x & 15;
  float4 acc = reinterpret_cast<const float4*>(bias)[o4];
#pragma unroll
  for (int c = 0; c < 64; ++c) {
    float xv = sx[ln * 65 + c];
    float gv = sg[ln * 65 + c];
    float4 v0 = reinterpret_cast<const float4*>(w0 + c * 64)[o4];
    float4 v1 = reinterpret_cast<const float4*>(w1 + c * 64)[o4];
    acc.x = fmaf(xv, v0.x, acc.x); acc.y = fmaf(xv, v0.y, acc.y);
    acc.z = fmaf(xv, v0.z, acc.z); acc.w = fmaf(xv, v0.w, acc.w);
    acc.x = fmaf(gv, v1.x, acc.x); acc.y = fmaf(gv, v1.y, acc.y);
    acc.z = fmaf(gv, v1.z, acc.z); acc.w = fmaf(gv, v1.w, acc.w);
  }
  reinterpret_cast<float4*>(out)[(size_t)(nb + ln) * 16 + o4] = acc;
}

extern "C" void kernel_launch(void* const* d_in, const int* in_sizes, int n_in,
                              void* d_out, int out_size, void* d_ws, size_t ws_size,
                              hipStream_t stream) {
  const float* x    = (const float*)d_in[0];
  const float* W0   = (const float*)d_in[1];
  const float* W1   = (const float*)d_in[2];
  const float* bias = (const float*)d_in[3];
  float* out = (float*)d_out;
  char* ws = (char*)d_ws;

  // workspace layout
  float* xf   = (float*)(ws);                       // 8192*64*4 = 2,097,152
  float* sq   = (float*)(ws + 2097152);             // 32,768
  int*   deg  = (int*)  (ws + 2129920);             // 32,768
  int*   idxf = (int*)  (ws + 2162688);             // 8192*9*4 = 294,912
  char*  pbase = ws + 2457600;                      // partial top-9 lists

  int P = 32;   // candidate chunks (occupancy lever for k_knn; merge needs <=32)
  while (P > 1) {
    size_t need = 2457600 + (size_t)P * N_NODES * KNN * 8;
    if (need <= ws_size) break;
    P >>= 1;
  }
  float* pd = (float*)pbase;
  int*   pi = (int*)(pbase + (size_t)P * N_NODES * KNN * 4);

  k_prep  <<<128, 256, 0, stream>>>(x, xf, sq, deg);
  k_knn   <<<dim3(32, P), 256, 0, stream>>>(xf, sq, pd, pi, P);
  k_merge <<<2048, 256, 0, stream>>>(pd, pi, idxf, deg, P);
  k_gout  <<<512, 256, 0, stream>>>(xf, idxf, deg, W0, W1, bias, out);
}